// Round 15
// baseline (350.364 us; speedup 1.0000x reference)
//
#include <hip/hip_runtime.h>

// ConvTranspose2d(64->64, k=3, s=2, p=1, out_pad=1) + bias + clip(0, 0.5)
// x: (32,64,128,128) f32, w: (64ci,64co,3,3) f32, b: (64) f32 -> out: (32,64,256,256) f32
//
// MFMA path: 9-tap parity decomposition, mfma_f32_32x32x16_f16, A=w-frag (rows=co),
// B=x-frag (cols=pixel). x split hi/lo f16 (2 products), w single RTN f16.
// Base = round-8 verified kernel (205 us). This round changes EXACTLY ONE thing:
//   __launch_bounds__(256,3) -> (256,4): 12 -> 16 waves/CU. More co-resident
//   blocks interleave read/MFMA/write phases per CU (smoother HBM mix).

#define CIN 64
#define COUT 64
#define HI 128
#define WI 128
#define HO 256
#define WO 256
#define HW (HI*WI)

typedef __attribute__((ext_vector_type(8))) _Float16 half8;
typedef __attribute__((ext_vector_type(16))) float f32x16;

__device__ __forceinline__ unsigned short f2h(float v) {
    _Float16 h = (_Float16)v;                       // v_cvt_f16_f32 (RTN)
    return __builtin_bit_cast(unsigned short, h);
}
__device__ __forceinline__ float h2f(unsigned short u) {
    return (float)__builtin_bit_cast(_Float16, u);
}

// ---- prep: wfrag[frag=(tap*4+ks)*2+ct][lane64][j8] f16 (verified r8) ----
__global__ void prep_wfrag(const float* __restrict__ w, unsigned short* __restrict__ wf) {
    int idx = blockIdx.x * 256 + threadIdx.x;
    if (idx >= 72 * 64) return;
    int lane = idx & 63;
    int frag = idx >> 6;
    int ct  = frag & 1;
    int ks  = (frag >> 1) & 3;
    int tap = frag >> 3;
    int co  = ct * 32 + (lane & 31);
    unsigned int packed[4];
    #pragma unroll
    for (int jp = 0; jp < 4; ++jp) {
        unsigned short h2[2];
        #pragma unroll
        for (int e = 0; e < 2; ++e) {
            int j = jp * 2 + e;
            int ci = ks * 16 + (lane >> 5) * 8 + j;
            h2[e] = f2h(w[(ci * COUT + co) * 9 + tap]);
        }
        packed[jp] = (unsigned)h2[0] | ((unsigned)h2[1] << 16);
    }
    ((uint4*)wf)[idx] = make_uint4(packed[0], packed[1], packed[2], packed[3]);
}

// ---- LDS f16: [buf2][hl2][row3][j33][ci16] ushort ----
#define L_JST 16
#define L_ROW (33*L_JST)    // 528
#define L_HL  (3*L_ROW)     // 1584
#define L_BUF (2*L_HL)      // 3168
#define L_TOT (2*L_BUF)     // 6336 ushorts = 12672 B

__global__ __launch_bounds__(256, 4) void convt_mfma_kernel(
    const float* __restrict__ x,
    const unsigned short* __restrict__ wf,
    const float* __restrict__ bias,
    float* __restrict__ out)
{
    __shared__ __align__(16) unsigned short lds[L_TOT];

    const int n    = blockIdx.z;
    const int i_in = blockIdx.y * 2;    // rows i_in..i_in+2 (2 owned + 1 halo)
    const int j0   = blockIdx.x * 32;   // cols j0..j0+32 (32 owned + 1 halo)

    const int tid = threadIdx.x;
    const int l   = tid & 63;
    const int wid = tid >> 6;
    const int ct  = wid & 1;            // co tile (32 co per wave)
    const int rp  = wid >> 1;           // owned input row within block (0,1)
    const int jj  = l & 31;
    const int ch  = l >> 5;             // ci-half selector

    const float* xn = x + (size_t)n * CIN * HW;

    // ---- staging: 3 rows * 33 j * 4 ci-quads = 396 items; cq fastest-in-lane
    //      keeps the global loads 64B-line coalesced ----
    float sv[2][4];
    int   soff[2];

    auto stage_load = [&](int ks) {
        #pragma unroll
        for (int it = 0; it < 2; ++it) {
            int q = tid + it * 256;
            soff[it] = -1;
            if (q < 396) {
                int cq  = q & 3;
                int p   = q >> 2;        // 0..98
                int j   = p % 33;
                int row = p / 33;
                soff[it] = row * L_ROW + j * L_JST + cq * 4;
                int gi = i_in + row, gj = j0 + j;
                float v0 = 0.f, v1 = 0.f, v2 = 0.f, v3 = 0.f;
                if (gi < HI && gj < WI) {
                    const float* s = xn + ((size_t)(ks * 16 + cq * 4) * HI + gi) * WI + gj;
                    v0 = s[0]; v1 = s[HW]; v2 = s[2 * HW]; v3 = s[3 * HW];
                }
                sv[it][0] = v0; sv[it][1] = v1; sv[it][2] = v2; sv[it][3] = v3;
            }
        }
    };
    auto stage_write = [&](int buf) {
        #pragma unroll
        for (int it = 0; it < 2; ++it) {
            if (soff[it] >= 0) {
                unsigned short h[4], g[4];
                #pragma unroll
                for (int c = 0; c < 4; ++c) {
                    h[c] = f2h(sv[it][c]);
                    g[c] = f2h(sv[it][c] - h2f(h[c]));
                }
                int base = buf * L_BUF + soff[it];
                *(uint2*)&lds[base]        = make_uint2((unsigned)h[0] | ((unsigned)h[1] << 16),
                                                        (unsigned)h[2] | ((unsigned)h[3] << 16));
                *(uint2*)&lds[base + L_HL] = make_uint2((unsigned)g[0] | ((unsigned)g[1] << 16),
                                                        (unsigned)g[2] | ((unsigned)g[3] << 16));
            }
        }
    };

    f32x16 acc[2][2];   // [dh][dw]
    #pragma unroll
    for (int a = 0; a < 2; ++a)
        #pragma unroll
        for (int b = 0; b < 2; ++b)
            #pragma unroll
            for (int e = 0; e < 16; ++e) acc[a][b][e] = 0.0f;

    stage_load(0);
    stage_write(0);
    __syncthreads();

    #pragma unroll 1
    for (int ks = 0; ks < 4; ++ks) {
        const int buf = ks & 1;

        // (1) weight fragments -> registers FIRST (their vmcnt wait must not
        //     drain the stage prefetch issued below)
        half8 wr[9];
        #pragma unroll
        for (int t = 0; t < 9; ++t)
            wr[t] = *(const half8*)&wf[(size_t)(((t * 4 + ks) * 2 + ct) * 512) + l * 8];

        // (2) issue next-kstep global prefetch (stays in flight through MFMAs)
        if (ks < 3) stage_load(ks + 1);

        // (3) MFMA burst: x from LDS (lgkmcnt only), w from registers
        const unsigned short* lb = lds + buf * L_BUF;

        #define DO_TAP(t, dh, dw)                                                    \
            {                                                                        \
                f32x16 a = acc[dh][dw];                                              \
                a = __builtin_amdgcn_mfma_f32_32x32x16_f16(wr[t], xh, a, 0, 0, 0);   \
                a = __builtin_amdgcn_mfma_f32_32x32x16_f16(wr[t], xl, a, 0, 0, 0);   \
                acc[dh][dw] = a;                                                     \
            }
        #define LOAD_XF(r, s)                                                        \
            half8 xh, xl;                                                            \
            {                                                                        \
                int xo = (rp + (r)) * L_ROW + (jj + (s)) * L_JST + ch * 8;           \
                xh = *(const half8*)&lb[xo];                                         \
                xl = *(const half8*)&lb[xo + L_HL];                                  \
            }

        { LOAD_XF(1, 1) DO_TAP(0, 1, 1) }                                   // t0
        { LOAD_XF(1, 0) DO_TAP(1, 1, 0) DO_TAP(2, 1, 1) }                   // t1,t2
        { LOAD_XF(0, 1) DO_TAP(3, 0, 1) DO_TAP(6, 1, 1) }                   // t3,t6
        { LOAD_XF(0, 0) DO_TAP(4, 0, 0) DO_TAP(5, 0, 1)
                        DO_TAP(7, 1, 0) DO_TAP(8, 1, 1) }                   // t4,5,7,8
        #undef DO_TAP
        #undef LOAD_XF

        // (4) drain stage loads, convert, write other buffer
        if (ks < 3) {
            stage_write(buf ^ 1);
            __syncthreads();
        }
    }

    // ---- epilogue: bias + clamp; lane = pixel -> coalesced dwordx2 stores ----
    float bco[16];
    #pragma unroll
    for (int rg = 0; rg < 16; ++rg)
        bco[rg] = bias[ct * 32 + (rg & 3) + 8 * (rg >> 2) + 4 * ch];

    float* outn = out + (size_t)n * COUT * HO * WO;
    const int ow0 = 2 * (j0 + jj);
    #pragma unroll
    for (int dh = 0; dh < 2; ++dh) {
        const int oh = 2 * (i_in + rp) + dh;
        #pragma unroll
        for (int rg = 0; rg < 16; ++rg) {
            const int co = ct * 32 + (rg & 3) + 8 * (rg >> 2) + 4 * ch;
            float v0 = acc[dh][0][rg] + bco[rg];
            float v1 = acc[dh][1][rg] + bco[rg];
            v0 = fminf(fmaxf(v0, 0.f), 0.5f);
            v1 = fminf(fmaxf(v1, 0.f), 0.5f);
            *(float2*)&outn[((size_t)co * HO + oh) * WO + ow0] = make_float2(v0, v1);
        }
    }
}

// ---------------- fallback (no-workspace): fp32 VALU kernel ----------------
#define TILE_I 4
#define TILE_J 16
#define HALO_I (TILE_I + 1)
#define HALO_J (TILE_J + 1)
#define XS_CSTRIDE 20
#define XS_RSTRIDE (HALO_I * XS_CSTRIDE)
#define XS_FLOATS (CIN * XS_RSTRIDE)

struct Regs { float wk[9]; float xa[2][HALO_J]; };

__device__ __forceinline__ void load_ci_fb(int ci, const float* __restrict__ wsrc,
                                           const float* xs, int warp, int lane, Regs& R) {
    #pragma unroll
    for (int k = 0; k < 9; ++k) R.wk[k] = wsrc[(ci * COUT + lane) * 9 + k];
    const float* xr = xs + ci * XS_RSTRIDE + warp * XS_CSTRIDE;
    #pragma unroll
    for (int rr = 0; rr < 2; ++rr) {
        const float4* p4 = reinterpret_cast<const float4*>(xr + rr * XS_CSTRIDE);
        #pragma unroll
        for (int q = 0; q < 4; ++q) {
            float4 v = p4[q];
            R.xa[rr][4*q+0] = v.x; R.xa[rr][4*q+1] = v.y;
            R.xa[rr][4*q+2] = v.z; R.xa[rr][4*q+3] = v.w;
        }
        R.xa[rr][16] = xr[rr * XS_CSTRIDE + 16];
    }
}

__device__ __forceinline__ void do_fma_fb(const Regs& R, float (&acc)[TILE_J][4]) {
    #pragma unroll
    for (int p = 0; p < TILE_J; ++p) {
        const float x00 = R.xa[0][p], x01 = R.xa[0][p+1];
        const float x10 = R.xa[1][p], x11 = R.xa[1][p+1];
        acc[p][0] += x00 * R.wk[4];
        acc[p][1] += x00 * R.wk[5]; acc[p][1] += x01 * R.wk[3];
        acc[p][2] += x00 * R.wk[7]; acc[p][2] += x10 * R.wk[1];
        acc[p][3] += x00 * R.wk[8]; acc[p][3] += x01 * R.wk[6];
        acc[p][3] += x10 * R.wk[2]; acc[p][3] += x11 * R.wk[0];
    }
}

__device__ __forceinline__ int es_slot_fb(int co, int oh, int g) {
    return co * 64 + oh * 8 + (g ^ (co & 7) ^ oh);
}

__global__ __launch_bounds__(256, 2) void convt_fallback_kernel(
    const float* __restrict__ x, const float* __restrict__ wsrc,
    const float* __restrict__ bias, float* __restrict__ out) {
    __shared__ __align__(16) float xs[XS_FLOATS];
    const int n = blockIdx.z, i0 = blockIdx.y * TILE_I, j0 = blockIdx.x * TILE_J;
    const float* xnf = x + (size_t)n * CIN * HI * WI;
    for (int f = threadIdx.x; f < CIN * HALO_I * HALO_J; f += 256) {
        int ci = f / (HALO_I * HALO_J);
        int rem = f - ci * (HALO_I * HALO_J);
        int r = rem / HALO_J, c = rem - r * HALO_J;
        int gi = i0 + r, gj = j0 + c;
        float v = 0.0f;
        if (gi < HI && gj < WI) v = xnf[(ci * HI + gi) * WI + gj];
        xs[ci * XS_RSTRIDE + r * XS_CSTRIDE + c] = v;
    }
    __syncthreads();
    const int warp = threadIdx.x >> 6, lane = threadIdx.x & 63;
    const float bcf = bias[lane];
    float acc[TILE_J][4];
    #pragma unroll
    for (int p = 0; p < TILE_J; ++p)
        #pragma unroll
        for (int q = 0; q < 4; ++q) acc[p][q] = 0.0f;
    Regs A, B1;
    load_ci_fb(0, wsrc, xs, warp, lane, A);
    #pragma unroll 1
    for (int ci = 0; ci < CIN; ci += 2) {
        load_ci_fb(ci + 1, wsrc, xs, warp, lane, B1);
        do_fma_fb(A, acc);
        int cin = (ci + 2 < CIN) ? ci + 2 : CIN - 1;
        load_ci_fb(cin, wsrc, xs, warp, lane, A);
        do_fma_fb(B1, acc);
    }
    float* outn = out + (size_t)n * COUT * HO * WO;
    const int ohb = 2 * i0, owb = 2 * j0;
    __syncthreads();
    float* es = xs;
    #pragma unroll 1
    for (int chunk = 0; chunk < 4; ++chunk) {
        const int c0 = chunk * 16;
        if ((lane & 48) == c0) {
            const int col = lane & 15;
            #pragma unroll
            for (int p = 0; p < TILE_J; ++p)
                #pragma unroll
                for (int q = 0; q < 4; ++q) {
                    const int ohl = warp * 2 + (q >> 1);
                    const int ow = 2 * p + (q & 1);
                    float v = acc[p][q] + bcf;
                    v = fminf(fmaxf(v, 0.0f), 0.5f);
                    es[es_slot_fb(col, ohl, ow >> 2) * 4 + (ow & 3)] = v;
                }
        }
        __syncthreads();
        {
            const int co_l = threadIdx.x >> 4;
            const int oh_l = (threadIdx.x & 15) >> 1;
            const int half = threadIdx.x & 1;
            float* dst = &outn[((size_t)(c0 + co_l) * HO + (ohb + oh_l)) * WO + owb + half * 16];
            #pragma unroll
            for (int qq = 0; qq < 4; ++qq) {
                const int g = half * 4 + qq;
                float4 v = *reinterpret_cast<const float4*>(&es[es_slot_fb(co_l, oh_l, g) * 4]);
                *reinterpret_cast<float4*>(dst + qq * 4) = v;
            }
        }
        __syncthreads();
    }
}

extern "C" void kernel_launch(void* const* d_in, const int* in_sizes, int n_in,
                              void* d_out, int out_size, void* d_ws, size_t ws_size,
                              hipStream_t stream) {
    const float* x = (const float*)d_in[0];
    const float* w = (const float*)d_in[1];
    const float* b = (const float*)d_in[2];
    float* out = (float*)d_out;
    const int B = in_sizes[0] / (CIN * HI * WI);  // 32

    const size_t wf_bytes = (size_t)72 * 64 * 8 * sizeof(unsigned short); // 73728
    if (ws_size >= wf_bytes) {
        unsigned short* wfrag = (unsigned short*)d_ws;
        prep_wfrag<<<18, 256, 0, stream>>>(w, wfrag);
        dim3 grid(WI / 32, HI / 2, B);            // (4, 64, 32) — r8 mapping
        convt_mfma_kernel<<<grid, 256, 0, stream>>>(x, wfrag, b, out);
    } else {
        dim3 grid(WI / TILE_J, HI / TILE_I, B);   // (8, 32, 32)
        convt_fallback_kernel<<<grid, 256, 0, stream>>>(x, w, b, out);
    }
}

// Round 16
// 203.570 us; speedup vs baseline: 1.7211x; 1.7211x over previous
//
#include <hip/hip_runtime.h>

// ConvTranspose2d(64->64, k=3, s=2, p=1, out_pad=1) + bias + clip(0, 0.5)
// x: (32,64,128,128) f32, w: (64ci,64co,3,3) f32, b: (64) f32 -> out: (32,64,256,256) f32
//
// MFMA path: 9-tap parity decomposition, mfma_f32_32x32x16_f16, A=w-frag (rows=co),
// B=x-frag (cols=pixel). x split hi/lo f16 (2 products), w single RTN f16.
// Base = round-8 verified kernel (205 us). Round-16: (256,4) occupancy WITHOUT spill:
//  - weight preload split: early {t0,t1,t2,t3,t6} (used in burst groups 1-3),
//    late {t4,t5,t7,t8} loaded after group 3 -> peak live ~115 VGPR < 128 cap
//  - soff[] cache dropped (recomputed in stage_write) to shave registers
// r15 measured: forced (256,4) with full wr[9] preload -> VGPR 64 + scratch spill
// (WRITE 524->780 MB), 350 us. This round removes the spill, keeps 16 waves/CU.

#define CIN 64
#define COUT 64
#define HI 128
#define WI 128
#define HO 256
#define WO 256
#define HW (HI*WI)

typedef __attribute__((ext_vector_type(8))) _Float16 half8;
typedef __attribute__((ext_vector_type(16))) float f32x16;

__device__ __forceinline__ unsigned short f2h(float v) {
    _Float16 h = (_Float16)v;                       // v_cvt_f16_f32 (RTN)
    return __builtin_bit_cast(unsigned short, h);
}
__device__ __forceinline__ float h2f(unsigned short u) {
    return (float)__builtin_bit_cast(_Float16, u);
}

// ---- prep: wfrag[frag=(tap*4+ks)*2+ct][lane64][j8] f16 (verified r8) ----
__global__ void prep_wfrag(const float* __restrict__ w, unsigned short* __restrict__ wf) {
    int idx = blockIdx.x * 256 + threadIdx.x;
    if (idx >= 72 * 64) return;
    int lane = idx & 63;
    int frag = idx >> 6;
    int ct  = frag & 1;
    int ks  = (frag >> 1) & 3;
    int tap = frag >> 3;
    int co  = ct * 32 + (lane & 31);
    unsigned int packed[4];
    #pragma unroll
    for (int jp = 0; jp < 4; ++jp) {
        unsigned short h2[2];
        #pragma unroll
        for (int e = 0; e < 2; ++e) {
            int j = jp * 2 + e;
            int ci = ks * 16 + (lane >> 5) * 8 + j;
            h2[e] = f2h(w[(ci * COUT + co) * 9 + tap]);
        }
        packed[jp] = (unsigned)h2[0] | ((unsigned)h2[1] << 16);
    }
    ((uint4*)wf)[idx] = make_uint4(packed[0], packed[1], packed[2], packed[3]);
}

// ---- LDS f16: [buf2][hl2][row3][j33][ci16] ushort ----
#define L_JST 16
#define L_ROW (33*L_JST)    // 528
#define L_HL  (3*L_ROW)     // 1584
#define L_BUF (2*L_HL)      // 3168
#define L_TOT (2*L_BUF)     // 6336 ushorts = 12672 B

__global__ __launch_bounds__(256, 4) void convt_mfma_kernel(
    const float* __restrict__ x,
    const unsigned short* __restrict__ wf,
    const float* __restrict__ bias,
    float* __restrict__ out)
{
    __shared__ __align__(16) unsigned short lds[L_TOT];

    const int n    = blockIdx.z;
    const int i_in = blockIdx.y * 2;    // rows i_in..i_in+2 (2 owned + 1 halo)
    const int j0   = blockIdx.x * 32;   // cols j0..j0+32 (32 owned + 1 halo)

    const int tid = threadIdx.x;
    const int l   = tid & 63;
    const int wid = tid >> 6;
    const int ct  = wid & 1;            // co tile (32 co per wave)
    const int rp  = wid >> 1;           // owned input row within block (0,1)
    const int jj  = l & 31;
    const int ch  = l >> 5;             // ci-half selector

    const float* xn = x + (size_t)n * CIN * HW;

    // ---- staging: 3 rows * 33 j * 4 ci-quads = 396 items; cq fastest-in-lane ----
    float sv[2][4];

    auto stage_load = [&](int ks) {
        #pragma unroll
        for (int it = 0; it < 2; ++it) {
            int q = tid + it * 256;
            if (q < 396) {
                int cq  = q & 3;
                int p   = q >> 2;        // 0..98
                int j   = p % 33;
                int row = p / 33;
                int gi = i_in + row, gj = j0 + j;
                float v0 = 0.f, v1 = 0.f, v2 = 0.f, v3 = 0.f;
                if (gi < HI && gj < WI) {
                    const float* s = xn + ((size_t)(ks * 16 + cq * 4) * HI + gi) * WI + gj;
                    v0 = s[0]; v1 = s[HW]; v2 = s[2 * HW]; v3 = s[3 * HW];
                }
                sv[it][0] = v0; sv[it][1] = v1; sv[it][2] = v2; sv[it][3] = v3;
            }
        }
    };
    auto stage_write = [&](int buf) {
        #pragma unroll
        for (int it = 0; it < 2; ++it) {
            int q = tid + it * 256;
            if (q < 396) {
                int cq  = q & 3;
                int p   = q >> 2;
                int j   = p % 33;
                int row = p / 33;
                int base = buf * L_BUF + row * L_ROW + j * L_JST + cq * 4;
                unsigned short h[4], g[4];
                #pragma unroll
                for (int c = 0; c < 4; ++c) {
                    h[c] = f2h(sv[it][c]);
                    g[c] = f2h(sv[it][c] - h2f(h[c]));
                }
                *(uint2*)&lds[base]        = make_uint2((unsigned)h[0] | ((unsigned)h[1] << 16),
                                                        (unsigned)h[2] | ((unsigned)h[3] << 16));
                *(uint2*)&lds[base + L_HL] = make_uint2((unsigned)g[0] | ((unsigned)g[1] << 16),
                                                        (unsigned)g[2] | ((unsigned)g[3] << 16));
            }
        }
    };

    f32x16 acc[2][2];   // [dh][dw]
    #pragma unroll
    for (int a = 0; a < 2; ++a)
        #pragma unroll
        for (int b = 0; b < 2; ++b)
            #pragma unroll
            for (int e = 0; e < 16; ++e) acc[a][b][e] = 0.0f;

    stage_load(0);
    stage_write(0);
    __syncthreads();

    #pragma unroll 1
    for (int ks = 0; ks < 4; ++ks) {
        const int buf = ks & 1;
        const unsigned short* wkb = wf + (size_t)(ks * 2 + ct) * 512 + (size_t)l * 8;

        // (1) EARLY weight frags: only taps used in burst groups 1-3
        //     ({t0,t1,t2,t3,t6} = 20 VGPR) -> issued before the stage prefetch
        half8 wr[9];
        wr[0] = *(const half8*)&wkb[0 * 8 * 512];
        wr[1] = *(const half8*)&wkb[1 * 8 * 512];
        wr[2] = *(const half8*)&wkb[2 * 8 * 512];
        wr[3] = *(const half8*)&wkb[3 * 8 * 512];
        wr[6] = *(const half8*)&wkb[6 * 8 * 512];

        // (2) issue next-kstep global prefetch (stays in flight through groups 1-3)
        if (ks < 3) stage_load(ks + 1);

        // (3) MFMA burst: x from LDS (lgkmcnt only), w from registers
        const unsigned short* lb = lds + buf * L_BUF;

        #define DO_TAP(t, dh, dw)                                                    \
            {                                                                        \
                f32x16 a = acc[dh][dw];                                              \
                a = __builtin_amdgcn_mfma_f32_32x32x16_f16(wr[t], xh, a, 0, 0, 0);   \
                a = __builtin_amdgcn_mfma_f32_32x32x16_f16(wr[t], xl, a, 0, 0, 0);   \
                acc[dh][dw] = a;                                                     \
            }
        #define LOAD_XF(r, s)                                                        \
            half8 xh, xl;                                                            \
            {                                                                        \
                int xo = (rp + (r)) * L_ROW + (jj + (s)) * L_JST + ch * 8;           \
                xh = *(const half8*)&lb[xo];                                         \
                xl = *(const half8*)&lb[xo + L_HL];                                  \
            }

        { LOAD_XF(1, 1) DO_TAP(0, 1, 1) }                                   // t0
        { LOAD_XF(1, 0) DO_TAP(1, 1, 0) DO_TAP(2, 1, 1) }                   // t1,t2
        { LOAD_XF(0, 1) DO_TAP(3, 0, 1) DO_TAP(6, 1, 1) }                   // t3,t6

        // (4) LATE weight frags for group 4 ({t4,t5,t7,t8} = 16 VGPR);
        //     early set is dead by now -> peak live stays under the 128 cap
        wr[4] = *(const half8*)&wkb[4 * 8 * 512];
        wr[5] = *(const half8*)&wkb[5 * 8 * 512];
        wr[7] = *(const half8*)&wkb[7 * 8 * 512];
        wr[8] = *(const half8*)&wkb[8 * 8 * 512];

        { LOAD_XF(0, 0) DO_TAP(4, 0, 0) DO_TAP(5, 0, 1)
                        DO_TAP(7, 1, 0) DO_TAP(8, 1, 1) }                   // t4,5,7,8
        #undef DO_TAP
        #undef LOAD_XF

        // (5) drain stage loads, convert, write other buffer
        if (ks < 3) {
            stage_write(buf ^ 1);
            __syncthreads();
        }
    }

    // ---- epilogue: bias + clamp; lane = pixel -> coalesced dwordx2 stores ----
    float bco[16];
    #pragma unroll
    for (int rg = 0; rg < 16; ++rg)
        bco[rg] = bias[ct * 32 + (rg & 3) + 8 * (rg >> 2) + 4 * ch];

    float* outn = out + (size_t)n * COUT * HO * WO;
    const int ow0 = 2 * (j0 + jj);
    #pragma unroll
    for (int dh = 0; dh < 2; ++dh) {
        const int oh = 2 * (i_in + rp) + dh;
        #pragma unroll
        for (int rg = 0; rg < 16; ++rg) {
            const int co = ct * 32 + (rg & 3) + 8 * (rg >> 2) + 4 * ch;
            float v0 = acc[dh][0][rg] + bco[rg];
            float v1 = acc[dh][1][rg] + bco[rg];
            v0 = fminf(fmaxf(v0, 0.f), 0.5f);
            v1 = fminf(fmaxf(v1, 0.f), 0.5f);
            *(float2*)&outn[((size_t)co * HO + oh) * WO + ow0] = make_float2(v0, v1);
        }
    }
}

// ---------------- fallback (no-workspace): fp32 VALU kernel ----------------
#define TILE_I 4
#define TILE_J 16
#define HALO_I (TILE_I + 1)
#define HALO_J (TILE_J + 1)
#define XS_CSTRIDE 20
#define XS_RSTRIDE (HALO_I * XS_CSTRIDE)
#define XS_FLOATS (CIN * XS_RSTRIDE)

struct Regs { float wk[9]; float xa[2][HALO_J]; };

__device__ __forceinline__ void load_ci_fb(int ci, const float* __restrict__ wsrc,
                                           const float* xs, int warp, int lane, Regs& R) {
    #pragma unroll
    for (int k = 0; k < 9; ++k) R.wk[k] = wsrc[(ci * COUT + lane) * 9 + k];
    const float* xr = xs + ci * XS_RSTRIDE + warp * XS_CSTRIDE;
    #pragma unroll
    for (int rr = 0; rr < 2; ++rr) {
        const float4* p4 = reinterpret_cast<const float4*>(xr + rr * XS_CSTRIDE);
        #pragma unroll
        for (int q = 0; q < 4; ++q) {
            float4 v = p4[q];
            R.xa[rr][4*q+0] = v.x; R.xa[rr][4*q+1] = v.y;
            R.xa[rr][4*q+2] = v.z; R.xa[rr][4*q+3] = v.w;
        }
        R.xa[rr][16] = xr[rr * XS_CSTRIDE + 16];
    }
}

__device__ __forceinline__ void do_fma_fb(const Regs& R, float (&acc)[TILE_J][4]) {
    #pragma unroll
    for (int p = 0; p < TILE_J; ++p) {
        const float x00 = R.xa[0][p], x01 = R.xa[0][p+1];
        const float x10 = R.xa[1][p], x11 = R.xa[1][p+1];
        acc[p][0] += x00 * R.wk[4];
        acc[p][1] += x00 * R.wk[5]; acc[p][1] += x01 * R.wk[3];
        acc[p][2] += x00 * R.wk[7]; acc[p][2] += x10 * R.wk[1];
        acc[p][3] += x00 * R.wk[8]; acc[p][3] += x01 * R.wk[6];
        acc[p][3] += x10 * R.wk[2]; acc[p][3] += x11 * R.wk[0];
    }
}

__device__ __forceinline__ int es_slot_fb(int co, int oh, int g) {
    return co * 64 + oh * 8 + (g ^ (co & 7) ^ oh);
}

__global__ __launch_bounds__(256, 2) void convt_fallback_kernel(
    const float* __restrict__ x, const float* __restrict__ wsrc,
    const float* __restrict__ bias, float* __restrict__ out) {
    __shared__ __align__(16) float xs[XS_FLOATS];
    const int n = blockIdx.z, i0 = blockIdx.y * TILE_I, j0 = blockIdx.x * TILE_J;
    const float* xnf = x + (size_t)n * CIN * HI * WI;
    for (int f = threadIdx.x; f < CIN * HALO_I * HALO_J; f += 256) {
        int ci = f / (HALO_I * HALO_J);
        int rem = f - ci * (HALO_I * HALO_J);
        int r = rem / HALO_J, c = rem - r * HALO_J;
        int gi = i0 + r, gj = j0 + c;
        float v = 0.0f;
        if (gi < HI && gj < WI) v = xnf[(ci * HI + gi) * WI + gj];
        xs[ci * XS_RSTRIDE + r * XS_CSTRIDE + c] = v;
    }
    __syncthreads();
    const int warp = threadIdx.x >> 6, lane = threadIdx.x & 63;
    const float bcf = bias[lane];
    float acc[TILE_J][4];
    #pragma unroll
    for (int p = 0; p < TILE_J; ++p)
        #pragma unroll
        for (int q = 0; q < 4; ++q) acc[p][q] = 0.0f;
    Regs A, B1;
    load_ci_fb(0, wsrc, xs, warp, lane, A);
    #pragma unroll 1
    for (int ci = 0; ci < CIN; ci += 2) {
        load_ci_fb(ci + 1, wsrc, xs, warp, lane, B1);
        do_fma_fb(A, acc);
        int cin = (ci + 2 < CIN) ? ci + 2 : CIN - 1;
        load_ci_fb(cin, wsrc, xs, warp, lane, A);
        do_fma_fb(B1, acc);
    }
    float* outn = out + (size_t)n * COUT * HO * WO;
    const int ohb = 2 * i0, owb = 2 * j0;
    __syncthreads();
    float* es = xs;
    #pragma unroll 1
    for (int chunk = 0; chunk < 4; ++chunk) {
        const int c0 = chunk * 16;
        if ((lane & 48) == c0) {
            const int col = lane & 15;
            #pragma unroll
            for (int p = 0; p < TILE_J; ++p)
                #pragma unroll
                for (int q = 0; q < 4; ++q) {
                    const int ohl = warp * 2 + (q >> 1);
                    const int ow = 2 * p + (q & 1);
                    float v = acc[p][q] + bcf;
                    v = fminf(fmaxf(v, 0.0f), 0.5f);
                    es[es_slot_fb(col, ohl, ow >> 2) * 4 + (ow & 3)] = v;
                }
        }
        __syncthreads();
        {
            const int co_l = threadIdx.x >> 4;
            const int oh_l = (threadIdx.x & 15) >> 1;
            const int half = threadIdx.x & 1;
            float* dst = &outn[((size_t)(c0 + co_l) * HO + (ohb + oh_l)) * WO + owb + half * 16];
            #pragma unroll
            for (int qq = 0; qq < 4; ++qq) {
                const int g = half * 4 + qq;
                float4 v = *reinterpret_cast<const float4*>(&es[es_slot_fb(co_l, oh_l, g) * 4]);
                *reinterpret_cast<float4*>(dst + qq * 4) = v;
            }
        }
        __syncthreads();
    }
}

extern "C" void kernel_launch(void* const* d_in, const int* in_sizes, int n_in,
                              void* d_out, int out_size, void* d_ws, size_t ws_size,
                              hipStream_t stream) {
    const float* x = (const float*)d_in[0];
    const float* w = (const float*)d_in[1];
    const float* b = (const float*)d_in[2];
    float* out = (float*)d_out;
    const int B = in_sizes[0] / (CIN * HI * WI);  // 32

    const size_t wf_bytes = (size_t)72 * 64 * 8 * sizeof(unsigned short); // 73728
    if (ws_size >= wf_bytes) {
        unsigned short* wfrag = (unsigned short*)d_ws;
        prep_wfrag<<<18, 256, 0, stream>>>(w, wfrag);
        dim3 grid(WI / 32, HI / 2, B);            // (4, 64, 32) — r8 mapping
        convt_mfma_kernel<<<grid, 256, 0, stream>>>(x, wfrag, b, out);
    } else {
        dim3 grid(WI / TILE_J, HI / TILE_I, B);   // (8, 32, 32)
        convt_fallback_kernel<<<grid, 256, 0, stream>>>(x, w, b, out);
    }
}

// Round 17
// 193.664 us; speedup vs baseline: 1.8091x; 1.0512x over previous
//
#include <hip/hip_runtime.h>

// ConvTranspose2d(64->64, k=3, s=2, p=1, out_pad=1) + bias + clip(0, 0.5)
// x: (32,64,128,128) f32, w: (64ci,64co,3,3) f32, b: (64) f32 -> out: (32,64,256,256) f32
//
// MFMA path: 9-tap parity decomposition, mfma_f32_32x32x16_f16, A=w-frag (rows=co),
// B=x-frag (cols=pixel). x split hi/lo f16 (2 products), w single RTN f16.
// Round-17: FULL-ROW blocks for HBM write locality. 1024 threads = 16 waves
// (rp2 x jg4 x ct2) cover 2 input rows x all 128 j x all 64 co, so each 1KB
// (co,oh) output row is produced by 4 lockstep waves of ONE block (one XCD L2)
// -> sequential write-back streams instead of 256B chunks from 4 different XCDs.
// Everything else identical to r16 (203.6 us): numerics, LDS scheme, w split
// preload, stage structure. Occupancy held at 16 waves/CU (128-VGPR cap).

#define CIN 64
#define COUT 64
#define HI 128
#define WI 128
#define HO 256
#define WO 256
#define HW (HI*WI)

typedef __attribute__((ext_vector_type(8))) _Float16 half8;
typedef __attribute__((ext_vector_type(16))) float f32x16;

__device__ __forceinline__ unsigned short f2h(float v) {
    _Float16 h = (_Float16)v;                       // v_cvt_f16_f32 (RTN)
    return __builtin_bit_cast(unsigned short, h);
}
__device__ __forceinline__ float h2f(unsigned short u) {
    return (float)__builtin_bit_cast(_Float16, u);
}

// ---- prep: wfrag[frag=(tap*4+ks)*2+ct][lane64][j8] f16 (verified r8) ----
__global__ void prep_wfrag(const float* __restrict__ w, unsigned short* __restrict__ wf) {
    int idx = blockIdx.x * 256 + threadIdx.x;
    if (idx >= 72 * 64) return;
    int lane = idx & 63;
    int frag = idx >> 6;
    int ct  = frag & 1;
    int ks  = (frag >> 1) & 3;
    int tap = frag >> 3;
    int co  = ct * 32 + (lane & 31);
    unsigned int packed[4];
    #pragma unroll
    for (int jp = 0; jp < 4; ++jp) {
        unsigned short h2[2];
        #pragma unroll
        for (int e = 0; e < 2; ++e) {
            int j = jp * 2 + e;
            int ci = ks * 16 + (lane >> 5) * 8 + j;
            h2[e] = f2h(w[(ci * COUT + co) * 9 + tap]);
        }
        packed[jp] = (unsigned)h2[0] | ((unsigned)h2[1] << 16);
    }
    ((uint4*)wf)[idx] = make_uint4(packed[0], packed[1], packed[2], packed[3]);
}

// ---- LDS f16: [buf2][hl2][row3][j129][ci16] ushort ----
#define L_JST 16
#define L_ROW (129*L_JST)   // 2064
#define L_HL  (3*L_ROW)     // 6192
#define L_BUF (2*L_HL)      // 12384
#define L_TOT (2*L_BUF)     // 24768 ushorts = 49536 B

__global__ __launch_bounds__(1024, 4) void convt_mfma_kernel(
    const float* __restrict__ x,
    const unsigned short* __restrict__ wf,
    const float* __restrict__ bias,
    float* __restrict__ out)
{
    __shared__ __align__(16) unsigned short lds[L_TOT];

    const int i_in = blockIdx.x * 2;    // rows i_in..i_in+2 (2 owned + 1 halo)
    const int n    = blockIdx.y;

    const int tid = threadIdx.x;
    const int l   = tid & 63;
    const int wid = tid >> 6;           // 0..15
    const int ct  = wid & 1;            // co tile (32 co per wave)
    const int jg  = (wid >> 1) & 3;     // j-group (32 j per wave)
    const int rp  = wid >> 3;           // owned input row within block (0,1)
    const int jj  = jg * 32 + (l & 31); // input col 0..127
    const int ch  = l >> 5;             // ci-half selector

    const float* xn = x + (size_t)n * CIN * HW;

    // ---- staging: 3 rows * 129 j * 4 ci-quads = 1548 items; cq fastest-in-lane ----
    float sv[2][4];

    auto stage_load = [&](int ks) {
        #pragma unroll
        for (int it = 0; it < 2; ++it) {
            int q = tid + it * 1024;
            if (q < 1548) {
                int cq  = q & 3;
                int p   = q >> 2;        // 0..386
                int j   = p % 129;
                int row = p / 129;
                int gi = i_in + row, gj = j;
                float v0 = 0.f, v1 = 0.f, v2 = 0.f, v3 = 0.f;
                if (gi < HI && gj < WI) {
                    const float* s = xn + ((size_t)(ks * 16 + cq * 4) * HI + gi) * WI + gj;
                    v0 = s[0]; v1 = s[HW]; v2 = s[2 * HW]; v3 = s[3 * HW];
                }
                sv[it][0] = v0; sv[it][1] = v1; sv[it][2] = v2; sv[it][3] = v3;
            }
        }
    };
    auto stage_write = [&](int buf) {
        #pragma unroll
        for (int it = 0; it < 2; ++it) {
            int q = tid + it * 1024;
            if (q < 1548) {
                int cq  = q & 3;
                int p   = q >> 2;
                int j   = p % 129;
                int row = p / 129;
                int base = buf * L_BUF + row * L_ROW + j * L_JST + cq * 4;
                unsigned short h[4], g[4];
                #pragma unroll
                for (int c = 0; c < 4; ++c) {
                    h[c] = f2h(sv[it][c]);
                    g[c] = f2h(sv[it][c] - h2f(h[c]));
                }
                *(uint2*)&lds[base]        = make_uint2((unsigned)h[0] | ((unsigned)h[1] << 16),
                                                        (unsigned)h[2] | ((unsigned)h[3] << 16));
                *(uint2*)&lds[base + L_HL] = make_uint2((unsigned)g[0] | ((unsigned)g[1] << 16),
                                                        (unsigned)g[2] | ((unsigned)g[3] << 16));
            }
        }
    };

    f32x16 acc[2][2];   // [dh][dw]
    #pragma unroll
    for (int a = 0; a < 2; ++a)
        #pragma unroll
        for (int b = 0; b < 2; ++b)
            #pragma unroll
            for (int e = 0; e < 16; ++e) acc[a][b][e] = 0.0f;

    stage_load(0);
    stage_write(0);
    __syncthreads();

    #pragma unroll 1
    for (int ks = 0; ks < 4; ++ks) {
        const int buf = ks & 1;
        const unsigned short* wkb = wf + (size_t)(ks * 2 + ct) * 512 + (size_t)l * 8;

        // (1) EARLY weight frags: taps for burst groups 1-3 ({t0,t1,t2,t3,t6})
        half8 wr[9];
        wr[0] = *(const half8*)&wkb[0 * 8 * 512];
        wr[1] = *(const half8*)&wkb[1 * 8 * 512];
        wr[2] = *(const half8*)&wkb[2 * 8 * 512];
        wr[3] = *(const half8*)&wkb[3 * 8 * 512];
        wr[6] = *(const half8*)&wkb[6 * 8 * 512];

        // (2) issue next-kstep global prefetch (stays in flight through groups 1-3)
        if (ks < 3) stage_load(ks + 1);

        // (3) MFMA burst: x from LDS (lgkmcnt only), w from registers
        const unsigned short* lb = lds + buf * L_BUF;

        #define DO_TAP(t, dh, dw)                                                    \
            {                                                                        \
                f32x16 a = acc[dh][dw];                                              \
                a = __builtin_amdgcn_mfma_f32_32x32x16_f16(wr[t], xh, a, 0, 0, 0);   \
                a = __builtin_amdgcn_mfma_f32_32x32x16_f16(wr[t], xl, a, 0, 0, 0);   \
                acc[dh][dw] = a;                                                     \
            }
        #define LOAD_XF(r, s)                                                        \
            half8 xh, xl;                                                            \
            {                                                                        \
                int xo = (rp + (r)) * L_ROW + (jj + (s)) * L_JST + ch * 8;           \
                xh = *(const half8*)&lb[xo];                                         \
                xl = *(const half8*)&lb[xo + L_HL];                                  \
            }

        { LOAD_XF(1, 1) DO_TAP(0, 1, 1) }                                   // t0
        { LOAD_XF(1, 0) DO_TAP(1, 1, 0) DO_TAP(2, 1, 1) }                   // t1,t2
        { LOAD_XF(0, 1) DO_TAP(3, 0, 1) DO_TAP(6, 1, 1) }                   // t3,t6

        // (4) LATE weight frags for group 4 ({t4,t5,t7,t8})
        wr[4] = *(const half8*)&wkb[4 * 8 * 512];
        wr[5] = *(const half8*)&wkb[5 * 8 * 512];
        wr[7] = *(const half8*)&wkb[7 * 8 * 512];
        wr[8] = *(const half8*)&wkb[8 * 8 * 512];

        { LOAD_XF(0, 0) DO_TAP(4, 0, 0) DO_TAP(5, 0, 1)
                        DO_TAP(7, 1, 0) DO_TAP(8, 1, 1) }                   // t4,5,7,8
        #undef DO_TAP
        #undef LOAD_XF

        // (5) drain stage loads, convert, write other buffer
        if (ks < 3) {
            stage_write(buf ^ 1);
            __syncthreads();
        }
    }

    // ---- epilogue: bias + clamp; lane = pixel -> coalesced dwordx2 stores;
    //      4 jg-waves jointly emit each full 1KB (co,oh) row ----
    float bco[16];
    #pragma unroll
    for (int rg = 0; rg < 16; ++rg)
        bco[rg] = bias[ct * 32 + (rg & 3) + 8 * (rg >> 2) + 4 * ch];

    float* outn = out + (size_t)n * COUT * HO * WO;
    const int ow0 = 2 * jj;
    #pragma unroll
    for (int dh = 0; dh < 2; ++dh) {
        const int oh = 2 * (i_in + rp) + dh;
        #pragma unroll
        for (int rg = 0; rg < 16; ++rg) {
            const int co = ct * 32 + (rg & 3) + 8 * (rg >> 2) + 4 * ch;
            float v0 = acc[dh][0][rg] + bco[rg];
            float v1 = acc[dh][1][rg] + bco[rg];
            v0 = fminf(fmaxf(v0, 0.f), 0.5f);
            v1 = fminf(fmaxf(v1, 0.f), 0.5f);
            *(float2*)&outn[((size_t)co * HO + oh) * WO + ow0] = make_float2(v0, v1);
        }
    }
}

// ---------------- fallback (no-workspace): fp32 VALU kernel ----------------
#define TILE_I 4
#define TILE_J 16
#define HALO_I (TILE_I + 1)
#define HALO_J (TILE_J + 1)
#define XS_CSTRIDE 20
#define XS_RSTRIDE (HALO_I * XS_CSTRIDE)
#define XS_FLOATS (CIN * XS_RSTRIDE)

struct Regs { float wk[9]; float xa[2][HALO_J]; };

__device__ __forceinline__ void load_ci_fb(int ci, const float* __restrict__ wsrc,
                                           const float* xs, int warp, int lane, Regs& R) {
    #pragma unroll
    for (int k = 0; k < 9; ++k) R.wk[k] = wsrc[(ci * COUT + lane) * 9 + k];
    const float* xr = xs + ci * XS_RSTRIDE + warp * XS_CSTRIDE;
    #pragma unroll
    for (int rr = 0; rr < 2; ++rr) {
        const float4* p4 = reinterpret_cast<const float4*>(xr + rr * XS_CSTRIDE);
        #pragma unroll
        for (int q = 0; q < 4; ++q) {
            float4 v = p4[q];
            R.xa[rr][4*q+0] = v.x; R.xa[rr][4*q+1] = v.y;
            R.xa[rr][4*q+2] = v.z; R.xa[rr][4*q+3] = v.w;
        }
        R.xa[rr][16] = xr[rr * XS_CSTRIDE + 16];
    }
}

__device__ __forceinline__ void do_fma_fb(const Regs& R, float (&acc)[TILE_J][4]) {
    #pragma unroll
    for (int p = 0; p < TILE_J; ++p) {
        const float x00 = R.xa[0][p], x01 = R.xa[0][p+1];
        const float x10 = R.xa[1][p], x11 = R.xa[1][p+1];
        acc[p][0] += x00 * R.wk[4];
        acc[p][1] += x00 * R.wk[5]; acc[p][1] += x01 * R.wk[3];
        acc[p][2] += x00 * R.wk[7]; acc[p][2] += x10 * R.wk[1];
        acc[p][3] += x00 * R.wk[8]; acc[p][3] += x01 * R.wk[6];
        acc[p][3] += x10 * R.wk[2]; acc[p][3] += x11 * R.wk[0];
    }
}

__device__ __forceinline__ int es_slot_fb(int co, int oh, int g) {
    return co * 64 + oh * 8 + (g ^ (co & 7) ^ oh);
}

__global__ __launch_bounds__(256, 2) void convt_fallback_kernel(
    const float* __restrict__ x, const float* __restrict__ wsrc,
    const float* __restrict__ bias, float* __restrict__ out) {
    __shared__ __align__(16) float xs[XS_FLOATS];
    const int n = blockIdx.z, i0 = blockIdx.y * TILE_I, j0 = blockIdx.x * TILE_J;
    const float* xnf = x + (size_t)n * CIN * HI * WI;
    for (int f = threadIdx.x; f < CIN * HALO_I * HALO_J; f += 256) {
        int ci = f / (HALO_I * HALO_J);
        int rem = f - ci * (HALO_I * HALO_J);
        int r = rem / HALO_J, c = rem - r * HALO_J;
        int gi = i0 + r, gj = j0 + c;
        float v = 0.0f;
        if (gi < HI && gj < WI) v = xnf[(ci * HI + gi) * WI + gj];
        xs[ci * XS_RSTRIDE + r * XS_CSTRIDE + c] = v;
    }
    __syncthreads();
    const int warp = threadIdx.x >> 6, lane = threadIdx.x & 63;
    const float bcf = bias[lane];
    float acc[TILE_J][4];
    #pragma unroll
    for (int p = 0; p < TILE_J; ++p)
        #pragma unroll
        for (int q = 0; q < 4; ++q) acc[p][q] = 0.0f;
    Regs A, B1;
    load_ci_fb(0, wsrc, xs, warp, lane, A);
    #pragma unroll 1
    for (int ci = 0; ci < CIN; ci += 2) {
        load_ci_fb(ci + 1, wsrc, xs, warp, lane, B1);
        do_fma_fb(A, acc);
        int cin = (ci + 2 < CIN) ? ci + 2 : CIN - 1;
        load_ci_fb(cin, wsrc, xs, warp, lane, A);
        do_fma_fb(B1, acc);
    }
    float* outn = out + (size_t)n * COUT * HO * WO;
    const int ohb = 2 * i0, owb = 2 * j0;
    __syncthreads();
    float* es = xs;
    #pragma unroll 1
    for (int chunk = 0; chunk < 4; ++chunk) {
        const int c0 = chunk * 16;
        if ((lane & 48) == c0) {
            const int col = lane & 15;
            #pragma unroll
            for (int p = 0; p < TILE_J; ++p)
                #pragma unroll
                for (int q = 0; q < 4; ++q) {
                    const int ohl = warp * 2 + (q >> 1);
                    const int ow = 2 * p + (q & 1);
                    float v = acc[p][q] + bcf;
                    v = fminf(fmaxf(v, 0.0f), 0.5f);
                    es[es_slot_fb(col, ohl, ow >> 2) * 4 + (ow & 3)] = v;
                }
        }
        __syncthreads();
        {
            const int co_l = threadIdx.x >> 4;
            const int oh_l = (threadIdx.x & 15) >> 1;
            const int half = threadIdx.x & 1;
            float* dst = &outn[((size_t)(c0 + co_l) * HO + (ohb + oh_l)) * WO + owb + half * 16];
            #pragma unroll
            for (int qq = 0; qq < 4; ++qq) {
                const int g = half * 4 + qq;
                float4 v = *reinterpret_cast<const float4*>(&es[es_slot_fb(co_l, oh_l, g) * 4]);
                *reinterpret_cast<float4*>(dst + qq * 4) = v;
            }
        }
        __syncthreads();
    }
}

extern "C" void kernel_launch(void* const* d_in, const int* in_sizes, int n_in,
                              void* d_out, int out_size, void* d_ws, size_t ws_size,
                              hipStream_t stream) {
    const float* x = (const float*)d_in[0];
    const float* w = (const float*)d_in[1];
    const float* b = (const float*)d_in[2];
    float* out = (float*)d_out;
    const int B = in_sizes[0] / (CIN * HI * WI);  // 32

    const size_t wf_bytes = (size_t)72 * 64 * 8 * sizeof(unsigned short); // 73728
    if (ws_size >= wf_bytes) {
        unsigned short* wfrag = (unsigned short*)d_ws;
        prep_wfrag<<<18, 256, 0, stream>>>(w, wfrag);
        dim3 grid(HI / 2, B);                     // (64, 32) — full-row blocks
        convt_mfma_kernel<<<grid, 1024, 0, stream>>>(x, wfrag, b, out);
    } else {
        dim3 grid(WI / TILE_J, HI / TILE_I, B);   // (8, 32, 32)
        convt_fallback_kernel<<<grid, 256, 0, stream>>>(x, w, b, out);
    }
}

// Round 18
// 166.109 us; speedup vs baseline: 2.1092x; 1.1659x over previous
//
#include <hip/hip_runtime.h>

// ConvTranspose2d(64->64, k=3, s=2, p=1, out_pad=1) + bias + clip(0, 0.5)
// x: (32,64,128,128) f32, w: (64ci,64co,3,3) f32, b: (64) f32 -> out: (32,64,256,256) f32
//
// MFMA path: 9-tap parity decomposition, mfma_f32_32x32x16_f16, A=w-frag (rows=co),
// B=x-frag (cols=pixel). x split hi/lo f16 (2 products), w single RTN f16.
// Base = round-17 (193.7 us best: full-row 1024-thread blocks, write locality).
// Round-18 changes EXACTLY ONE thing: output stores -> __builtin_nontemporal_store
// (write-once data streams past L2/L3: no write-allocate pollution of the x/w
// working set, lines write-combine toward DRAM in issue order).

#define CIN 64
#define COUT 64
#define HI 128
#define WI 128
#define HO 256
#define WO 256
#define HW (HI*WI)

typedef __attribute__((ext_vector_type(8))) _Float16 half8;
typedef __attribute__((ext_vector_type(16))) float f32x16;
typedef __attribute__((ext_vector_type(2)))  float f32x2;

__device__ __forceinline__ unsigned short f2h(float v) {
    _Float16 h = (_Float16)v;                       // v_cvt_f16_f32 (RTN)
    return __builtin_bit_cast(unsigned short, h);
}
__device__ __forceinline__ float h2f(unsigned short u) {
    return (float)__builtin_bit_cast(_Float16, u);
}

// ---- prep: wfrag[frag=(tap*4+ks)*2+ct][lane64][j8] f16 (verified r8) ----
__global__ void prep_wfrag(const float* __restrict__ w, unsigned short* __restrict__ wf) {
    int idx = blockIdx.x * 256 + threadIdx.x;
    if (idx >= 72 * 64) return;
    int lane = idx & 63;
    int frag = idx >> 6;
    int ct  = frag & 1;
    int ks  = (frag >> 1) & 3;
    int tap = frag >> 3;
    int co  = ct * 32 + (lane & 31);
    unsigned int packed[4];
    #pragma unroll
    for (int jp = 0; jp < 4; ++jp) {
        unsigned short h2[2];
        #pragma unroll
        for (int e = 0; e < 2; ++e) {
            int j = jp * 2 + e;
            int ci = ks * 16 + (lane >> 5) * 8 + j;
            h2[e] = f2h(w[(ci * COUT + co) * 9 + tap]);
        }
        packed[jp] = (unsigned)h2[0] | ((unsigned)h2[1] << 16);
    }
    ((uint4*)wf)[idx] = make_uint4(packed[0], packed[1], packed[2], packed[3]);
}

// ---- LDS f16: [buf2][hl2][row3][j129][ci16] ushort ----
#define L_JST 16
#define L_ROW (129*L_JST)   // 2064
#define L_HL  (3*L_ROW)     // 6192
#define L_BUF (2*L_HL)      // 12384
#define L_TOT (2*L_BUF)     // 24768 ushorts = 49536 B

__global__ __launch_bounds__(1024, 4) void convt_mfma_kernel(
    const float* __restrict__ x,
    const unsigned short* __restrict__ wf,
    const float* __restrict__ bias,
    float* __restrict__ out)
{
    __shared__ __align__(16) unsigned short lds[L_TOT];

    const int i_in = blockIdx.x * 2;    // rows i_in..i_in+2 (2 owned + 1 halo)
    const int n    = blockIdx.y;

    const int tid = threadIdx.x;
    const int l   = tid & 63;
    const int wid = tid >> 6;           // 0..15
    const int ct  = wid & 1;            // co tile (32 co per wave)
    const int jg  = (wid >> 1) & 3;     // j-group (32 j per wave)
    const int rp  = wid >> 3;           // owned input row within block (0,1)
    const int jj  = jg * 32 + (l & 31); // input col 0..127
    const int ch  = l >> 5;             // ci-half selector

    const float* xn = x + (size_t)n * CIN * HW;

    // ---- staging: 3 rows * 129 j * 4 ci-quads = 1548 items; cq fastest-in-lane ----
    float sv[2][4];

    auto stage_load = [&](int ks) {
        #pragma unroll
        for (int it = 0; it < 2; ++it) {
            int q = tid + it * 1024;
            if (q < 1548) {
                int cq  = q & 3;
                int p   = q >> 2;        // 0..386
                int j   = p % 129;
                int row = p / 129;
                int gi = i_in + row, gj = j;
                float v0 = 0.f, v1 = 0.f, v2 = 0.f, v3 = 0.f;
                if (gi < HI && gj < WI) {
                    const float* s = xn + ((size_t)(ks * 16 + cq * 4) * HI + gi) * WI + gj;
                    v0 = s[0]; v1 = s[HW]; v2 = s[2 * HW]; v3 = s[3 * HW];
                }
                sv[it][0] = v0; sv[it][1] = v1; sv[it][2] = v2; sv[it][3] = v3;
            }
        }
    };
    auto stage_write = [&](int buf) {
        #pragma unroll
        for (int it = 0; it < 2; ++it) {
            int q = tid + it * 1024;
            if (q < 1548) {
                int cq  = q & 3;
                int p   = q >> 2;
                int j   = p % 129;
                int row = p / 129;
                int base = buf * L_BUF + row * L_ROW + j * L_JST + cq * 4;
                unsigned short h[4], g[4];
                #pragma unroll
                for (int c = 0; c < 4; ++c) {
                    h[c] = f2h(sv[it][c]);
                    g[c] = f2h(sv[it][c] - h2f(h[c]));
                }
                *(uint2*)&lds[base]        = make_uint2((unsigned)h[0] | ((unsigned)h[1] << 16),
                                                        (unsigned)h[2] | ((unsigned)h[3] << 16));
                *(uint2*)&lds[base + L_HL] = make_uint2((unsigned)g[0] | ((unsigned)g[1] << 16),
                                                        (unsigned)g[2] | ((unsigned)g[3] << 16));
            }
        }
    };

    f32x16 acc[2][2];   // [dh][dw]
    #pragma unroll
    for (int a = 0; a < 2; ++a)
        #pragma unroll
        for (int b = 0; b < 2; ++b)
            #pragma unroll
            for (int e = 0; e < 16; ++e) acc[a][b][e] = 0.0f;

    stage_load(0);
    stage_write(0);
    __syncthreads();

    #pragma unroll 1
    for (int ks = 0; ks < 4; ++ks) {
        const int buf = ks & 1;
        const unsigned short* wkb = wf + (size_t)(ks * 2 + ct) * 512 + (size_t)l * 8;

        // (1) EARLY weight frags: taps for burst groups 1-3 ({t0,t1,t2,t3,t6})
        half8 wr[9];
        wr[0] = *(const half8*)&wkb[0 * 8 * 512];
        wr[1] = *(const half8*)&wkb[1 * 8 * 512];
        wr[2] = *(const half8*)&wkb[2 * 8 * 512];
        wr[3] = *(const half8*)&wkb[3 * 8 * 512];
        wr[6] = *(const half8*)&wkb[6 * 8 * 512];

        // (2) issue next-kstep global prefetch (stays in flight through groups 1-3)
        if (ks < 3) stage_load(ks + 1);

        // (3) MFMA burst: x from LDS (lgkmcnt only), w from registers
        const unsigned short* lb = lds + buf * L_BUF;

        #define DO_TAP(t, dh, dw)                                                    \
            {                                                                        \
                f32x16 a = acc[dh][dw];                                              \
                a = __builtin_amdgcn_mfma_f32_32x32x16_f16(wr[t], xh, a, 0, 0, 0);   \
                a = __builtin_amdgcn_mfma_f32_32x32x16_f16(wr[t], xl, a, 0, 0, 0);   \
                acc[dh][dw] = a;                                                     \
            }
        #define LOAD_XF(r, s)                                                        \
            half8 xh, xl;                                                            \
            {                                                                        \
                int xo = (rp + (r)) * L_ROW + (jj + (s)) * L_JST + ch * 8;           \
                xh = *(const half8*)&lb[xo];                                         \
                xl = *(const half8*)&lb[xo + L_HL];                                  \
            }

        { LOAD_XF(1, 1) DO_TAP(0, 1, 1) }                                   // t0
        { LOAD_XF(1, 0) DO_TAP(1, 1, 0) DO_TAP(2, 1, 1) }                   // t1,t2
        { LOAD_XF(0, 1) DO_TAP(3, 0, 1) DO_TAP(6, 1, 1) }                   // t3,t6

        // (4) LATE weight frags for group 4 ({t4,t5,t7,t8})
        wr[4] = *(const half8*)&wkb[4 * 8 * 512];
        wr[5] = *(const half8*)&wkb[5 * 8 * 512];
        wr[7] = *(const half8*)&wkb[7 * 8 * 512];
        wr[8] = *(const half8*)&wkb[8 * 8 * 512];

        { LOAD_XF(0, 0) DO_TAP(4, 0, 0) DO_TAP(5, 0, 1)
                        DO_TAP(7, 1, 0) DO_TAP(8, 1, 1) }                   // t4,5,7,8
        #undef DO_TAP
        #undef LOAD_XF

        // (5) drain stage loads, convert, write other buffer
        if (ks < 3) {
            stage_write(buf ^ 1);
            __syncthreads();
        }
    }

    // ---- epilogue: bias + clamp; NONTEMPORAL dwordx2 stores (write-once stream);
    //      4 jg-waves jointly emit each full 1KB (co,oh) row ----
    float bco[16];
    #pragma unroll
    for (int rg = 0; rg < 16; ++rg)
        bco[rg] = bias[ct * 32 + (rg & 3) + 8 * (rg >> 2) + 4 * ch];

    float* outn = out + (size_t)n * COUT * HO * WO;
    const int ow0 = 2 * jj;
    #pragma unroll
    for (int dh = 0; dh < 2; ++dh) {
        const int oh = 2 * (i_in + rp) + dh;
        #pragma unroll
        for (int rg = 0; rg < 16; ++rg) {
            const int co = ct * 32 + (rg & 3) + 8 * (rg >> 2) + 4 * ch;
            float v0 = acc[dh][0][rg] + bco[rg];
            float v1 = acc[dh][1][rg] + bco[rg];
            v0 = fminf(fmaxf(v0, 0.f), 0.5f);
            v1 = fminf(fmaxf(v1, 0.f), 0.5f);
            f32x2 pv; pv[0] = v0; pv[1] = v1;
            __builtin_nontemporal_store(pv,
                (f32x2*)&outn[((size_t)co * HO + oh) * WO + ow0]);
        }
    }
}

// ---------------- fallback (no-workspace): fp32 VALU kernel ----------------
#define TILE_I 4
#define TILE_J 16
#define HALO_I (TILE_I + 1)
#define HALO_J (TILE_J + 1)
#define XS_CSTRIDE 20
#define XS_RSTRIDE (HALO_I * XS_CSTRIDE)
#define XS_FLOATS (CIN * XS_RSTRIDE)

struct Regs { float wk[9]; float xa[2][HALO_J]; };

__device__ __forceinline__ void load_ci_fb(int ci, const float* __restrict__ wsrc,
                                           const float* xs, int warp, int lane, Regs& R) {
    #pragma unroll
    for (int k = 0; k < 9; ++k) R.wk[k] = wsrc[(ci * COUT + lane) * 9 + k];
    const float* xr = xs + ci * XS_RSTRIDE + warp * XS_CSTRIDE;
    #pragma unroll
    for (int rr = 0; rr < 2; ++rr) {
        const float4* p4 = reinterpret_cast<const float4*>(xr + rr * XS_CSTRIDE);
        #pragma unroll
        for (int q = 0; q < 4; ++q) {
            float4 v = p4[q];
            R.xa[rr][4*q+0] = v.x; R.xa[rr][4*q+1] = v.y;
            R.xa[rr][4*q+2] = v.z; R.xa[rr][4*q+3] = v.w;
        }
        R.xa[rr][16] = xr[rr * XS_CSTRIDE + 16];
    }
}

__device__ __forceinline__ void do_fma_fb(const Regs& R, float (&acc)[TILE_J][4]) {
    #pragma unroll
    for (int p = 0; p < TILE_J; ++p) {
        const float x00 = R.xa[0][p], x01 = R.xa[0][p+1];
        const float x10 = R.xa[1][p], x11 = R.xa[1][p+1];
        acc[p][0] += x00 * R.wk[4];
        acc[p][1] += x00 * R.wk[5]; acc[p][1] += x01 * R.wk[3];
        acc[p][2] += x00 * R.wk[7]; acc[p][2] += x10 * R.wk[1];
        acc[p][3] += x00 * R.wk[8]; acc[p][3] += x01 * R.wk[6];
        acc[p][3] += x10 * R.wk[2]; acc[p][3] += x11 * R.wk[0];
    }
}

__device__ __forceinline__ int es_slot_fb(int co, int oh, int g) {
    return co * 64 + oh * 8 + (g ^ (co & 7) ^ oh);
}

__global__ __launch_bounds__(256, 2) void convt_fallback_kernel(
    const float* __restrict__ x, const float* __restrict__ wsrc,
    const float* __restrict__ bias, float* __restrict__ out) {
    __shared__ __align__(16) float xs[XS_FLOATS];
    const int n = blockIdx.z, i0 = blockIdx.y * TILE_I, j0 = blockIdx.x * TILE_J;
    const float* xnf = x + (size_t)n * CIN * HI * WI;
    for (int f = threadIdx.x; f < CIN * HALO_I * HALO_J; f += 256) {
        int ci = f / (HALO_I * HALO_J);
        int rem = f - ci * (HALO_I * HALO_J);
        int r = rem / HALO_J, c = rem - r * HALO_J;
        int gi = i0 + r, gj = j0 + c;
        float v = 0.0f;
        if (gi < HI && gj < WI) v = xnf[(ci * HI + gi) * WI + gj];
        xs[ci * XS_RSTRIDE + r * XS_CSTRIDE + c] = v;
    }
    __syncthreads();
    const int warp = threadIdx.x >> 6, lane = threadIdx.x & 63;
    const float bcf = bias[lane];
    float acc[TILE_J][4];
    #pragma unroll
    for (int p = 0; p < TILE_J; ++p)
        #pragma unroll
        for (int q = 0; q < 4; ++q) acc[p][q] = 0.0f;
    Regs A, B1;
    load_ci_fb(0, wsrc, xs, warp, lane, A);
    #pragma unroll 1
    for (int ci = 0; ci < CIN; ci += 2) {
        load_ci_fb(ci + 1, wsrc, xs, warp, lane, B1);
        do_fma_fb(A, acc);
        int cin = (ci + 2 < CIN) ? ci + 2 : CIN - 1;
        load_ci_fb(cin, wsrc, xs, warp, lane, A);
        do_fma_fb(B1, acc);
    }
    float* outn = out + (size_t)n * COUT * HO * WO;
    const int ohb = 2 * i0, owb = 2 * j0;
    __syncthreads();
    float* es = xs;
    #pragma unroll 1
    for (int chunk = 0; chunk < 4; ++chunk) {
        const int c0 = chunk * 16;
        if ((lane & 48) == c0) {
            const int col = lane & 15;
            #pragma unroll
            for (int p = 0; p < TILE_J; ++p)
                #pragma unroll
                for (int q = 0; q < 4; ++q) {
                    const int ohl = warp * 2 + (q >> 1);
                    const int ow = 2 * p + (q & 1);
                    float v = acc[p][q] + bcf;
                    v = fminf(fmaxf(v, 0.0f), 0.5f);
                    es[es_slot_fb(col, ohl, ow >> 2) * 4 + (ow & 3)] = v;
                }
        }
        __syncthreads();
        {
            const int co_l = threadIdx.x >> 4;
            const int oh_l = (threadIdx.x & 15) >> 1;
            const int half = threadIdx.x & 1;
            float* dst = &outn[((size_t)(c0 + co_l) * HO + (ohb + oh_l)) * WO + owb + half * 16];
            #pragma unroll
            for (int qq = 0; qq < 4; ++qq) {
                const int g = half * 4 + qq;
                float4 v = *reinterpret_cast<const float4*>(&es[es_slot_fb(co_l, oh_l, g) * 4]);
                *reinterpret_cast<float4*>(dst + qq * 4) = v;
            }
        }
        __syncthreads();
    }
}

extern "C" void kernel_launch(void* const* d_in, const int* in_sizes, int n_in,
                              void* d_out, int out_size, void* d_ws, size_t ws_size,
                              hipStream_t stream) {
    const float* x = (const float*)d_in[0];
    const float* w = (const float*)d_in[1];
    const float* b = (const float*)d_in[2];
    float* out = (float*)d_out;
    const int B = in_sizes[0] / (CIN * HI * WI);  // 32

    const size_t wf_bytes = (size_t)72 * 64 * 8 * sizeof(unsigned short); // 73728
    if (ws_size >= wf_bytes) {
        unsigned short* wfrag = (unsigned short*)d_ws;
        prep_wfrag<<<18, 256, 0, stream>>>(w, wfrag);
        dim3 grid(HI / 2, B);                     // (64, 32) — full-row blocks
        convt_mfma_kernel<<<grid, 1024, 0, stream>>>(x, wfrag, b, out);
    } else {
        dim3 grid(WI / TILE_J, HI / TILE_I, B);   // (8, 32, 32)
        convt_fallback_kernel<<<grid, 256, 0, stream>>>(x, w, b, out);
    }
}

// Round 19
// 164.760 us; speedup vs baseline: 2.1265x; 1.0082x over previous
//
#include <hip/hip_runtime.h>

// ConvTranspose2d(64->64, k=3, s=2, p=1, out_pad=1) + bias + clip(0, 0.5)
// x: (32,64,128,128) f32, w: (64ci,64co,3,3) f32, b: (64) f32 -> out: (32,64,256,256) f32
//
// MFMA path: 9-tap parity decomposition, mfma_f32_32x32x16_f16, A=w-frag (rows=co),
// B=x-frag (cols=pixel). x split hi/lo f16 (2 products), w single RTN f16.
// Base = r18 (166.1 us best: full-row blocks + NT stores). Round-19: restore
// cross-block phase overlap. 512-thread blocks (8 waves = jg4 x ct2) own ONE
// input row (stage 2: owned + halo) x 128 j x all co -> block still writes its
// two 1KB (co,oh) rows alone (r17 locality kept), NT stores kept, and
// launch_bounds(512,4) gives 2 resident blocks/CU: one block's terminal store
// burst overlaps the other's stage+MFMA (fixes the 1-resident duty cycle).

#define CIN 64
#define COUT 64
#define HI 128
#define WI 128
#define HO 256
#define WO 256
#define HW (HI*WI)

typedef __attribute__((ext_vector_type(8))) _Float16 half8;
typedef __attribute__((ext_vector_type(16))) float f32x16;
typedef __attribute__((ext_vector_type(2)))  float f32x2;

__device__ __forceinline__ unsigned short f2h(float v) {
    _Float16 h = (_Float16)v;                       // v_cvt_f16_f32 (RTN)
    return __builtin_bit_cast(unsigned short, h);
}
__device__ __forceinline__ float h2f(unsigned short u) {
    return (float)__builtin_bit_cast(_Float16, u);
}

// ---- prep: wfrag[frag=(tap*4+ks)*2+ct][lane64][j8] f16 (verified r8) ----
__global__ void prep_wfrag(const float* __restrict__ w, unsigned short* __restrict__ wf) {
    int idx = blockIdx.x * 256 + threadIdx.x;
    if (idx >= 72 * 64) return;
    int lane = idx & 63;
    int frag = idx >> 6;
    int ct  = frag & 1;
    int ks  = (frag >> 1) & 3;
    int tap = frag >> 3;
    int co  = ct * 32 + (lane & 31);
    unsigned int packed[4];
    #pragma unroll
    for (int jp = 0; jp < 4; ++jp) {
        unsigned short h2[2];
        #pragma unroll
        for (int e = 0; e < 2; ++e) {
            int j = jp * 2 + e;
            int ci = ks * 16 + (lane >> 5) * 8 + j;
            h2[e] = f2h(w[(ci * COUT + co) * 9 + tap]);
        }
        packed[jp] = (unsigned)h2[0] | ((unsigned)h2[1] << 16);
    }
    ((uint4*)wf)[idx] = make_uint4(packed[0], packed[1], packed[2], packed[3]);
}

// ---- LDS f16: [buf2][hl2][row2][j129][ci16] ushort ----
#define L_JST 16
#define L_ROW (129*L_JST)   // 2064
#define L_HL  (2*L_ROW)     // 4128 (2 rows: owned + halo)
#define L_BUF (2*L_HL)      // 8256
#define L_TOT (2*L_BUF)     // 16512 ushorts = 33024 B

__global__ __launch_bounds__(512, 4) void convt_mfma_kernel(
    const float* __restrict__ x,
    const unsigned short* __restrict__ wf,
    const float* __restrict__ bias,
    float* __restrict__ out)
{
    __shared__ __align__(16) unsigned short lds[L_TOT];

    const int i_in = blockIdx.x;        // owned input row (stages i_in, i_in+1)
    const int n    = blockIdx.y;

    const int tid = threadIdx.x;
    const int l   = tid & 63;
    const int wid = tid >> 6;           // 0..7
    const int ct  = wid & 1;            // co tile (32 co per wave)
    const int jg  = wid >> 1;           // j-group (32 j per wave)
    const int jj  = jg * 32 + (l & 31); // input col 0..127
    const int ch  = l >> 5;             // ci-half selector

    const float* xn = x + (size_t)n * CIN * HW;

    // ---- staging: 2 rows * 129 j * 4 ci-quads = 1032 items; cq fastest-in-lane ----
    float sv[3][4];

    auto stage_load = [&](int ks) {
        #pragma unroll
        for (int it = 0; it < 3; ++it) {
            int q = tid + it * 512;
            if (q < 1032) {
                int cq  = q & 3;
                int p   = q >> 2;        // 0..257
                int j   = p % 129;
                int row = p / 129;
                int gi = i_in + row, gj = j;
                float v0 = 0.f, v1 = 0.f, v2 = 0.f, v3 = 0.f;
                if (gi < HI && gj < WI) {
                    const float* s = xn + ((size_t)(ks * 16 + cq * 4) * HI + gi) * WI + gj;
                    v0 = s[0]; v1 = s[HW]; v2 = s[2 * HW]; v3 = s[3 * HW];
                }
                sv[it][0] = v0; sv[it][1] = v1; sv[it][2] = v2; sv[it][3] = v3;
            }
        }
    };
    auto stage_write = [&](int buf) {
        #pragma unroll
        for (int it = 0; it < 3; ++it) {
            int q = tid + it * 512;
            if (q < 1032) {
                int cq  = q & 3;
                int p   = q >> 2;
                int j   = p % 129;
                int row = p / 129;
                int base = buf * L_BUF + row * L_ROW + j * L_JST + cq * 4;
                unsigned short h[4], g[4];
                #pragma unroll
                for (int c = 0; c < 4; ++c) {
                    h[c] = f2h(sv[it][c]);
                    g[c] = f2h(sv[it][c] - h2f(h[c]));
                }
                *(uint2*)&lds[base]        = make_uint2((unsigned)h[0] | ((unsigned)h[1] << 16),
                                                        (unsigned)h[2] | ((unsigned)h[3] << 16));
                *(uint2*)&lds[base + L_HL] = make_uint2((unsigned)g[0] | ((unsigned)g[1] << 16),
                                                        (unsigned)g[2] | ((unsigned)g[3] << 16));
            }
        }
    };

    f32x16 acc[2][2];   // [dh][dw]
    #pragma unroll
    for (int a = 0; a < 2; ++a)
        #pragma unroll
        for (int b = 0; b < 2; ++b)
            #pragma unroll
            for (int e = 0; e < 16; ++e) acc[a][b][e] = 0.0f;

    stage_load(0);
    stage_write(0);
    __syncthreads();

    #pragma unroll 1
    for (int ks = 0; ks < 4; ++ks) {
        const int buf = ks & 1;
        const unsigned short* wkb = wf + (size_t)(ks * 2 + ct) * 512 + (size_t)l * 8;

        // (1) EARLY weight frags: taps for burst groups 1-3 ({t0,t1,t2,t3,t6})
        half8 wr[9];
        wr[0] = *(const half8*)&wkb[0 * 8 * 512];
        wr[1] = *(const half8*)&wkb[1 * 8 * 512];
        wr[2] = *(const half8*)&wkb[2 * 8 * 512];
        wr[3] = *(const half8*)&wkb[3 * 8 * 512];
        wr[6] = *(const half8*)&wkb[6 * 8 * 512];

        // (2) issue next-kstep global prefetch (stays in flight through groups 1-3)
        if (ks < 3) stage_load(ks + 1);

        // (3) MFMA burst: x from LDS (lgkmcnt only), w from registers
        const unsigned short* lb = lds + buf * L_BUF;

        #define DO_TAP(t, dh, dw)                                                    \
            {                                                                        \
                f32x16 a = acc[dh][dw];                                              \
                a = __builtin_amdgcn_mfma_f32_32x32x16_f16(wr[t], xh, a, 0, 0, 0);   \
                a = __builtin_amdgcn_mfma_f32_32x32x16_f16(wr[t], xl, a, 0, 0, 0);   \
                acc[dh][dw] = a;                                                     \
            }
        #define LOAD_XF(r, s)                                                        \
            half8 xh, xl;                                                            \
            {                                                                        \
                int xo = (r) * L_ROW + (jj + (s)) * L_JST + ch * 8;                  \
                xh = *(const half8*)&lb[xo];                                         \
                xl = *(const half8*)&lb[xo + L_HL];                                  \
            }

        { LOAD_XF(1, 1) DO_TAP(0, 1, 1) }                                   // t0
        { LOAD_XF(1, 0) DO_TAP(1, 1, 0) DO_TAP(2, 1, 1) }                   // t1,t2
        { LOAD_XF(0, 1) DO_TAP(3, 0, 1) DO_TAP(6, 1, 1) }                   // t3,t6

        // (4) LATE weight frags for group 4 ({t4,t5,t7,t8})
        wr[4] = *(const half8*)&wkb[4 * 8 * 512];
        wr[5] = *(const half8*)&wkb[5 * 8 * 512];
        wr[7] = *(const half8*)&wkb[7 * 8 * 512];
        wr[8] = *(const half8*)&wkb[8 * 8 * 512];

        { LOAD_XF(0, 0) DO_TAP(4, 0, 0) DO_TAP(5, 0, 1)
                        DO_TAP(7, 1, 0) DO_TAP(8, 1, 1) }                   // t4,5,7,8
        #undef DO_TAP
        #undef LOAD_XF

        // (5) drain stage loads, convert, write other buffer
        if (ks < 3) {
            stage_write(buf ^ 1);
            __syncthreads();
        }
    }

    // ---- epilogue: bias + clamp; NONTEMPORAL dwordx2 stores; this block alone
    //      emits its two full 1KB (co,oh) rows (oh = 2*i_in + dh) ----
    float bco[16];
    #pragma unroll
    for (int rg = 0; rg < 16; ++rg)
        bco[rg] = bias[ct * 32 + (rg & 3) + 8 * (rg >> 2) + 4 * ch];

    float* outn = out + (size_t)n * COUT * HO * WO;
    const int ow0 = 2 * jj;
    #pragma unroll
    for (int dh = 0; dh < 2; ++dh) {
        const int oh = 2 * i_in + dh;
        #pragma unroll
        for (int rg = 0; rg < 16; ++rg) {
            const int co = ct * 32 + (rg & 3) + 8 * (rg >> 2) + 4 * ch;
            float v0 = acc[dh][0][rg] + bco[rg];
            float v1 = acc[dh][1][rg] + bco[rg];
            v0 = fminf(fmaxf(v0, 0.f), 0.5f);
            v1 = fminf(fmaxf(v1, 0.f), 0.5f);
            f32x2 pv; pv[0] = v0; pv[1] = v1;
            __builtin_nontemporal_store(pv,
                (f32x2*)&outn[((size_t)co * HO + oh) * WO + ow0]);
        }
    }
}

// ---------------- fallback (no-workspace): fp32 VALU kernel ----------------
#define TILE_I 4
#define TILE_J 16
#define HALO_I (TILE_I + 1)
#define HALO_J (TILE_J + 1)
#define XS_CSTRIDE 20
#define XS_RSTRIDE (HALO_I * XS_CSTRIDE)
#define XS_FLOATS (CIN * XS_RSTRIDE)

struct Regs { float wk[9]; float xa[2][HALO_J]; };

__device__ __forceinline__ void load_ci_fb(int ci, const float* __restrict__ wsrc,
                                           const float* xs, int warp, int lane, Regs& R) {
    #pragma unroll
    for (int k = 0; k < 9; ++k) R.wk[k] = wsrc[(ci * COUT + lane) * 9 + k];
    const float* xr = xs + ci * XS_RSTRIDE + warp * XS_CSTRIDE;
    #pragma unroll
    for (int rr = 0; rr < 2; ++rr) {
        const float4* p4 = reinterpret_cast<const float4*>(xr + rr * XS_CSTRIDE);
        #pragma unroll
        for (int q = 0; q < 4; ++q) {
            float4 v = p4[q];
            R.xa[rr][4*q+0] = v.x; R.xa[rr][4*q+1] = v.y;
            R.xa[rr][4*q+2] = v.z; R.xa[rr][4*q+3] = v.w;
        }
        R.xa[rr][16] = xr[rr * XS_CSTRIDE + 16];
    }
}

__device__ __forceinline__ void do_fma_fb(const Regs& R, float (&acc)[TILE_J][4]) {
    #pragma unroll
    for (int p = 0; p < TILE_J; ++p) {
        const float x00 = R.xa[0][p], x01 = R.xa[0][p+1];
        const float x10 = R.xa[1][p], x11 = R.xa[1][p+1];
        acc[p][0] += x00 * R.wk[4];
        acc[p][1] += x00 * R.wk[5]; acc[p][1] += x01 * R.wk[3];
        acc[p][2] += x00 * R.wk[7]; acc[p][2] += x10 * R.wk[1];
        acc[p][3] += x00 * R.wk[8]; acc[p][3] += x01 * R.wk[6];
        acc[p][3] += x10 * R.wk[2]; acc[p][3] += x11 * R.wk[0];
    }
}

__device__ __forceinline__ int es_slot_fb(int co, int oh, int g) {
    return co * 64 + oh * 8 + (g ^ (co & 7) ^ oh);
}

__global__ __launch_bounds__(256, 2) void convt_fallback_kernel(
    const float* __restrict__ x, const float* __restrict__ wsrc,
    const float* __restrict__ bias, float* __restrict__ out) {
    __shared__ __align__(16) float xs[XS_FLOATS];
    const int n = blockIdx.z, i0 = blockIdx.y * TILE_I, j0 = blockIdx.x * TILE_J;
    const float* xnf = x + (size_t)n * CIN * HI * WI;
    for (int f = threadIdx.x; f < CIN * HALO_I * HALO_J; f += 256) {
        int ci = f / (HALO_I * HALO_J);
        int rem = f - ci * (HALO_I * HALO_J);
        int r = rem / HALO_J, c = rem - r * HALO_J;
        int gi = i0 + r, gj = j0 + c;
        float v = 0.0f;
        if (gi < HI && gj < WI) v = xnf[(ci * HI + gi) * WI + gj];
        xs[ci * XS_RSTRIDE + r * XS_CSTRIDE + c] = v;
    }
    __syncthreads();
    const int warp = threadIdx.x >> 6, lane = threadIdx.x & 63;
    const float bcf = bias[lane];
    float acc[TILE_J][4];
    #pragma unroll
    for (int p = 0; p < TILE_J; ++p)
        #pragma unroll
        for (int q = 0; q < 4; ++q) acc[p][q] = 0.0f;
    Regs A, B1;
    load_ci_fb(0, wsrc, xs, warp, lane, A);
    #pragma unroll 1
    for (int ci = 0; ci < CIN; ci += 2) {
        load_ci_fb(ci + 1, wsrc, xs, warp, lane, B1);
        do_fma_fb(A, acc);
        int cin = (ci + 2 < CIN) ? ci + 2 : CIN - 1;
        load_ci_fb(cin, wsrc, xs, warp, lane, A);
        do_fma_fb(B1, acc);
    }
    float* outn = out + (size_t)n * COUT * HO * WO;
    const int ohb = 2 * i0, owb = 2 * j0;
    __syncthreads();
    float* es = xs;
    #pragma unroll 1
    for (int chunk = 0; chunk < 4; ++chunk) {
        const int c0 = chunk * 16;
        if ((lane & 48) == c0) {
            const int col = lane & 15;
            #pragma unroll
            for (int p = 0; p < TILE_J; ++p)
                #pragma unroll
                for (int q = 0; q < 4; ++q) {
                    const int ohl = warp * 2 + (q >> 1);
                    const int ow = 2 * p + (q & 1);
                    float v = acc[p][q] + bcf;
                    v = fminf(fmaxf(v, 0.0f), 0.5f);
                    es[es_slot_fb(col, ohl, ow >> 2) * 4 + (ow & 3)] = v;
                }
        }
        __syncthreads();
        {
            const int co_l = threadIdx.x >> 4;
            const int oh_l = (threadIdx.x & 15) >> 1;
            const int half = threadIdx.x & 1;
            float* dst = &outn[((size_t)(c0 + co_l) * HO + (ohb + oh_l)) * WO + owb + half * 16];
            #pragma unroll
            for (int qq = 0; qq < 4; ++qq) {
                const int g = half * 4 + qq;
                float4 v = *reinterpret_cast<const float4*>(&es[es_slot_fb(co_l, oh_l, g) * 4]);
                *reinterpret_cast<float4*>(dst + qq * 4) = v;
            }
        }
        __syncthreads();
    }
}

extern "C" void kernel_launch(void* const* d_in, const int* in_sizes, int n_in,
                              void* d_out, int out_size, void* d_ws, size_t ws_size,
                              hipStream_t stream) {
    const float* x = (const float*)d_in[0];
    const float* w = (const float*)d_in[1];
    const float* b = (const float*)d_in[2];
    float* out = (float*)d_out;
    const int B = in_sizes[0] / (CIN * HI * WI);  // 32

    const size_t wf_bytes = (size_t)72 * 64 * 8 * sizeof(unsigned short); // 73728
    if (ws_size >= wf_bytes) {
        unsigned short* wfrag = (unsigned short*)d_ws;
        prep_wfrag<<<18, 256, 0, stream>>>(w, wfrag);
        dim3 grid(HI, B);                         // (128, 32) — one-row blocks
        convt_mfma_kernel<<<grid, 512, 0, stream>>>(x, wfrag, b, out);
    } else {
        dim3 grid(WI / TILE_J, HI / TILE_I, B);   // (8, 32, 32)
        convt_fallback_kernel<<<grid, 256, 0, stream>>>(x, w, b, out);
    }
}